// Round 9
// baseline (34.832 us; speedup 1.0000x reference)
//
#include <hip/hip_runtime.h>

namespace {
constexpr int kM = 4, kJ = 2, kI = 3, kL = 2, kW = 9;
constexpr float kInvLn2 = 1.4426950408889634f;

typedef float v2f __attribute__((ext_vector_type(2)));  // -> v_pk_*_f32

__device__ __forceinline__ float fexp2(float x) { return __builtin_amdgcn_exp2f(x); }
// wave-synchronous LDS fence: all this wave's outstanding LDS ops complete.
__device__ __forceinline__ void lds_fence() {
  asm volatile("s_waitcnt lgkmcnt(0)" ::: "memory");
}

// dp layout (72 floats), per m (16 floats at m*16), j-packed {j0,j1} pairs:
//   [c0, c1, w0n, w1n, C00, C01, C10, C11]
// completed-square match score (negated, log2-scaled):
//   msN = w0n*(s0-c0)^2 + w1n*(s1-c1)^2,  w*n = -(1-g*)/ln2  (msN <= 0)
// C (head∘body, gavg-folded) unscaled. D[m][l] at 64 + m*2 + l.
__global__ void prep_kernel(const float* __restrict__ constants,
                            const float* __restrict__ gammas,
                            const float* __restrict__ W_body,
                            const float* __restrict__ b_body,
                            const float* __restrict__ W_head,
                            const float* __restrict__ b_head,
                            float* __restrict__ dp) {
  const int t = threadIdx.x;
  if (t < 8) {
    const int mj = t, m = t >> 1, j = t & 1;
    const float g0 = fminf(fmaxf(gammas[mj * kL + 0], 0.f), 1.f);
    const float g1 = fminf(fmaxf(gammas[mj * kL + 1], 0.f), 1.f);
    const float w0 = 1.f - g0, w1 = 1.f - g1;
    const float c0 = constants[mj * kL + 0], c1 = constants[mj * kL + 1];
    const float gavg = 0.5f * (g0 + g1);
    float* base = dp + m * 16;
    base[0 * 2 + j] = c0;
    base[1 * 2 + j] = c1;
    base[2 * 2 + j] = -w0 * kInvLn2;
    base[3 * 2 + j] = -w1 * kInvLn2;
    for (int l = 0; l < kL; ++l)
      for (int lp = 0; lp < kL; ++lp) {
        float acc = 0.f;
        for (int i = 0; i < kI; ++i)
          acc += W_head[(m * kL + l) * kI + i] * W_body[(mj * kI + i) * kL + lp];
        base[(4 + l * kL + lp) * 2 + j] = gavg * acc;
      }
  } else if (t < 12) {
    const int m = t - 8;
    for (int l = 0; l < kL; ++l) {
      float d = b_head[m * kL + l];
      for (int j = 0; j < kJ; ++j) {
        const int mj = m * kJ + j;
        const float g0 = fminf(fmaxf(gammas[mj * kL + 0], 0.f), 1.f);
        const float g1 = fminf(fmaxf(gammas[mj * kL + 1], 0.f), 1.f);
        const float gavg = 0.5f * (g0 + g1);
        float acc = 0.f;
        for (int i = 0; i < kI; ++i)
          acc += W_head[(m * kL + l) * kI + i] * b_body[mj * kI + i];
        d += gavg * acc;
      }
      dp[64 + m * kL + l] = d;
    }
  }
}

// R8 compute body unchanged. New: wave-private LDS staging so ALL global
// traffic is coalesced (loads: 9x dwordx2 each hitting 8 lines, was ~60;
// stores: 9x dword each hitting 4 lines, was ~36). No __syncthreads —
// each wave stages its own 64 rows in its own 4608B LDS region.
__global__ __launch_bounds__(256, 4) void algelogic_main(
    const float* __restrict__ state, const float* __restrict__ dp,
    float* __restrict__ out) {
  __shared__ float lds[4 * 1152];           // 4 waves x 4608B
  const int lane = threadIdx.x & 63;
  const int wid = threadIdx.x >> 6;
  float* wb = lds + wid * 1152;
  const long chunk = ((long)blockIdx.x * 4 + wid) * 64;  // first elem of wave

  // ---- stage 64 rows (4608B) via coalesced float2 loads ----
  {
    const float2* g2 = reinterpret_cast<const float2*>(state) + chunk * 9;
    float2* w2 = reinterpret_cast<float2*>(wb);
    float2 stg[9];
#pragma unroll
    for (int k = 0; k < 9; ++k) stg[k] = g2[k * 64 + lane];   // 512B/instr apart
#pragma unroll
    for (int k = 0; k < 9; ++k) w2[k * 64 + lane] = stg[k];   // 2-way banks: free
  }
  lds_fence();

  // ---- per-thread row from LDS (stride 18 dwords, 4-way: ~1.58x on 9 reads) ----
  v2f s[kW];
  {
    const float* srow = wb + lane * 18;
#pragma unroll
    for (int w = 0; w < kW; ++w) {
      const float2 v = *reinterpret_cast<const float2*>(srow + 2 * w);
      v2f t; t.x = v.x; t.y = v.y;
      s[w] = t;
    }
  }

  // ---- compute: identical to R8 ----
  float Cs = 0.f, X0 = 0.f, X1 = 0.f, K = 0.f;
#pragma unroll
  for (int m = 0; m < kM; ++m) {
    const float* P = dp + m * 16;          // uniform -> s_load
    v2f c0;  c0.x = P[0];  c0.y = P[1];
    v2f c1;  c1.x = P[2];  c1.y = P[3];
    v2f w0n; w0n.x = P[4]; w0n.y = P[5];
    v2f w1n; w1n.x = P[6]; w1n.y = P[7];

    v2f psum = {1e-35f, 1e-35f};
    v2f pb0 = {0.f, 0.f}, pb1 = {0.f, 0.f}, pmq = {0.f, 0.f};
#pragma unroll
    for (int w = 0; w < kW; ++w) {
      const float sx = s[w].x, sy = s[w].y;
      const v2f d0 = sx - c0;
      const v2f d1 = sy - c1;
      v2f msN = (d0 * d0) * w0n;
      msN += (d1 * d1) * w1n;
      v2f e; e.x = fexp2(msN.x); e.y = fexp2(msN.y);
      psum += e;
      pb0 += e * sx;
      pb1 += e * sy;
      pmq += e * msN;
    }

    v2f rinv;
    rinv.x = __builtin_amdgcn_rcpf(psum.x);
    rinv.y = __builtin_amdgcn_rcpf(psum.y);
    const v2f bb0 = pb0 * rinv, bb1 = pb1 * rinv;
    const v2f mqv = pmq * rinv;
    const float conf = fexp2(mqv.x + mqv.y);

    v2f C00; C00.x = P[8];  C00.y = P[9];
    v2f C01; C01.x = P[10]; C01.y = P[11];
    v2f C10; C10.x = P[12]; C10.y = P[13];
    v2f C11; C11.x = P[14]; C11.y = P[15];
    const v2f t0 = C00 * bb0 + C01 * bb1;
    const v2f t1 = C10 * bb0 + C11 * bb1;
    const float r0 = dp[64 + m * 2 + 0] + t0.x + t0.y;
    const float r1 = dp[64 + m * 2 + 1] + t1.x + t1.y;

    Cs += conf;
    X0 = fmaf(conf, r0, X0);
    X1 = fmaf(conf, r1, X1);
    K = fmaf(conf, fmaf(r0, r0, r1 * r1), K);
  }

  // ---- out: stage row in LDS (reuse region), then coalesced dword stores ----
  const float X02 = 2.f * X0, X12 = 2.f * X1;
  {
    float* wo = wb + lane * 9;             // banks 9t%32: conflict-free
#pragma unroll
    for (int w = 0; w < kW; ++w) {
      const v2f q = s[w] * s[w];
      wo[w] = fmaf(X02, s[w].x, fmaf(X12, s[w].y, fmaf(-Cs, q.x + q.y, -K)));
    }
  }
  lds_fence();
  {
    float* og = out + chunk * 9;
#pragma unroll
    for (int k = 0; k < 9; ++k)            // 256B/instr contiguous stores
      og[k * 64 + lane] = wb[k * 64 + lane];
  }
}
}  // namespace

extern "C" void kernel_launch(void* const* d_in, const int* in_sizes, int n_in,
                              void* d_out, int out_size, void* d_ws, size_t ws_size,
                              hipStream_t stream) {
  const float* state     = (const float*)d_in[0];
  const float* constants = (const float*)d_in[1];
  const float* gammas    = (const float*)d_in[2];
  const float* W_body    = (const float*)d_in[3];
  const float* b_body    = (const float*)d_in[4];
  const float* W_head    = (const float*)d_in[5];
  const float* b_head    = (const float*)d_in[6];
  float* out = (float*)d_out;
  float* dp  = (float*)d_ws;

  const int B = in_sizes[0] / (kW * kL);   // 1048576
  hipLaunchKernelGGL(prep_kernel, dim3(1), dim3(64), 0, stream,
                     constants, gammas, W_body, b_body, W_head, b_head, dp);
  hipLaunchKernelGGL(algelogic_main, dim3(B / 256), dim3(256), 0, stream,
                     state, dp, out);
}

// Round 10
// 32.104 us; speedup vs baseline: 1.0850x; 1.0850x over previous
//
#include <hip/hip_runtime.h>

namespace {
constexpr int kM = 4, kJ = 2, kI = 3, kL = 2, kW = 9;
constexpr float kInvLn2 = 1.4426950408889634f;

typedef float v2f __attribute__((ext_vector_type(2)));  // -> v_pk_*_f32

__device__ __forceinline__ float fexp2(float x) { return __builtin_amdgcn_exp2f(x); }

// Single fused kernel. Per-block param fold (two short chains on two
// DIFFERENT waves, running while all waves' state loads are in flight),
// one barrier, then the R8 compute body with params served from LDS
// (uniform-address ds_read broadcast: ~40cy, vs ~250cy global s_load).
//
// sdp layout (72 floats), per m (16 floats at m*16), j-packed {j0,j1}:
//   [c0, c1, w0n, w1n, C00, C01, C10, C11]
// completed-square match score (negated, log2-scaled):
//   msN = w0n*(s0-c0)^2 + w1n*(s1-c1)^2,  w*n = -(1-g*)/ln2  (msN <= 0)
// D[m][l] at 64 + m*2 + l.
__global__ __launch_bounds__(256, 4) void algelogic_one(
    const float* __restrict__ state,
    const float* __restrict__ constants,
    const float* __restrict__ gammas,
    const float* __restrict__ W_body,
    const float* __restrict__ b_body,
    const float* __restrict__ W_head,
    const float* __restrict__ b_head,
    float* __restrict__ out) {
  __shared__ float sdp[72];
  const int t = threadIdx.x;
  const int b = blockIdx.x * 256 + t;

  // ---- issue state loads immediately (in flight during the fold) ----
  const float2* sr = reinterpret_cast<const float2*>(state) + (size_t)b * kW;
  v2f s[kW];
#pragma unroll
  for (int w = 0; w < kW; ++w) {
    const float2 v = sr[w];
    v2f x; x.x = v.x; x.y = v.y;
    s[w] = x;
  }

  // ---- param fold: wave 0 (lanes 0-7) coeffs+C; wave 1 (lanes 0-3) D ----
  if (t < 8) {
    const int mj = t, m = t >> 1, j = t & 1;
    const float g0 = fminf(fmaxf(gammas[mj * kL + 0], 0.f), 1.f);
    const float g1 = fminf(fmaxf(gammas[mj * kL + 1], 0.f), 1.f);
    const float w0 = 1.f - g0, w1 = 1.f - g1;
    const float c0 = constants[mj * kL + 0], c1 = constants[mj * kL + 1];
    const float gavg = 0.5f * (g0 + g1);
    float* base = sdp + m * 16;
    base[0 * 2 + j] = c0;
    base[1 * 2 + j] = c1;
    base[2 * 2 + j] = -w0 * kInvLn2;      // w0n
    base[3 * 2 + j] = -w1 * kInvLn2;      // w1n
#pragma unroll
    for (int l = 0; l < kL; ++l)
#pragma unroll
      for (int lp = 0; lp < kL; ++lp) {
        float acc = 0.f;
#pragma unroll
        for (int i = 0; i < kI; ++i)
          acc += W_head[(m * kL + l) * kI + i] * W_body[(mj * kI + i) * kL + lp];
        base[(4 + l * kL + lp) * 2 + j] = gavg * acc;   // C[l][lp]
      }
  } else if (t >= 64 && t < 68) {
    const int m = t - 64;
#pragma unroll
    for (int l = 0; l < kL; ++l) {
      float d = b_head[m * kL + l];
#pragma unroll
      for (int j = 0; j < kJ; ++j) {
        const int mj = m * kJ + j;
        const float g0 = fminf(fmaxf(gammas[mj * kL + 0], 0.f), 1.f);
        const float g1 = fminf(fmaxf(gammas[mj * kL + 1], 0.f), 1.f);
        const float gavg = 0.5f * (g0 + g1);
        float acc = 0.f;
#pragma unroll
        for (int i = 0; i < kI; ++i)
          acc += W_head[(m * kL + l) * kI + i] * b_body[mj * kI + i];
        d += gavg * acc;
      }
      sdp[64 + m * kL + l] = d;
    }
  }
  __syncthreads();

  // ---- compute (R8 body; params via uniform ds_read broadcast) ----
  float Cs = 0.f, X0 = 0.f, X1 = 0.f, K = 0.f;
#pragma unroll
  for (int m = 0; m < kM; ++m) {
    const float* P = sdp + m * 16;
    v2f c0;  c0.x = P[0];  c0.y = P[1];
    v2f c1;  c1.x = P[2];  c1.y = P[3];
    v2f w0n; w0n.x = P[4]; w0n.y = P[5];
    v2f w1n; w1n.x = P[6]; w1n.y = P[7];

    v2f psum = {1e-35f, 1e-35f};   // guard: rcp never sees denormal/0
    v2f pb0 = {0.f, 0.f}, pb1 = {0.f, 0.f}, pmq = {0.f, 0.f};
#pragma unroll
    for (int w = 0; w < kW; ++w) {
      const float sx = s[w].x, sy = s[w].y;
      const v2f d0 = sx - c0;
      const v2f d1 = sy - c1;
      v2f msN = (d0 * d0) * w0n;
      msN += (d1 * d1) * w1n;
      v2f e; e.x = fexp2(msN.x); e.y = fexp2(msN.y);
      psum += e;
      pb0 += e * sx;
      pb1 += e * sy;
      pmq += e * msN;                      // = -Σ e·ms/ln2
    }

    v2f rinv;
    rinv.x = __builtin_amdgcn_rcpf(psum.x);
    rinv.y = __builtin_amdgcn_rcpf(psum.y);
    const v2f bb0 = pb0 * rinv, bb1 = pb1 * rinv;
    const v2f mqv = pmq * rinv;
    const float conf = fexp2(mqv.x + mqv.y);   // exp2(-mq/ln2) = exp(-mq)

    v2f C00; C00.x = P[8];  C00.y = P[9];
    v2f C01; C01.x = P[10]; C01.y = P[11];
    v2f C10; C10.x = P[12]; C10.y = P[13];
    v2f C11; C11.x = P[14]; C11.y = P[15];
    const v2f t0 = C00 * bb0 + C01 * bb1;
    const v2f t1 = C10 * bb0 + C11 * bb1;
    const float r0 = sdp[64 + m * 2 + 0] + t0.x + t0.y;
    const float r1 = sdp[64 + m * 2 + 1] + t1.x + t1.y;

    Cs += conf;
    X0 = fmaf(conf, r0, X0);
    X1 = fmaf(conf, r1, X1);
    K = fmaf(conf, fmaf(r0, r0, r1 * r1), K);
  }

  const float X02 = 2.f * X0, X12 = 2.f * X1;
  float* orow = out + (size_t)b * kW;
#pragma unroll
  for (int w = 0; w < kW; ++w) {
    const v2f q = s[w] * s[w];
    // out = 2X0*s0 + 2X1*s1 - Cs*(s0^2+s1^2) - K
    orow[w] = fmaf(X02, s[w].x, fmaf(X12, s[w].y, fmaf(-Cs, q.x + q.y, -K)));
  }
}
}  // namespace

extern "C" void kernel_launch(void* const* d_in, const int* in_sizes, int n_in,
                              void* d_out, int out_size, void* d_ws, size_t ws_size,
                              hipStream_t stream) {
  const float* state     = (const float*)d_in[0];
  const float* constants = (const float*)d_in[1];
  const float* gammas    = (const float*)d_in[2];
  const float* W_body    = (const float*)d_in[3];
  const float* b_body    = (const float*)d_in[4];
  const float* W_head    = (const float*)d_in[5];
  const float* b_head    = (const float*)d_in[6];
  float* out = (float*)d_out;

  const int B = in_sizes[0] / (kW * kL);   // 1048576
  hipLaunchKernelGGL(algelogic_one, dim3(B / 256), dim3(256), 0, stream,
                     state, constants, gammas, W_body, b_body, W_head, b_head, out);
}